// Round 9
// baseline (68.092 us; speedup 1.0000x reference)
//
#include <hip/hip_runtime.h>
#include <hip/hip_bf16.h>
#include <stdint.h>

#define B_ 2
#define N_ 3000
#define F_ 64
#define H_ 4
#define D_ 32
#define K_ 128          // H_*D_ output feature cols
#define KT_ 9           // 9 k-tiles of 16 -> 144 cols (128 feat + 4 denom + 12 pad)
#define NCHP_ 96        // padded m-chunks (3072 m; 94 real + 2 zero)
#define BITSW_ 96       // bit-words per adjacency row (padded, words 94/95 = 0)
#define NROWT_ 188      // ceil(3000/16) 16-row tiles per batch
#define S4_ 4           // split-K factor: each split = exactly 24 chunks
#define PT_ 2304        // partial tile floats: 36 x 64
#define CHB_ 9216       // bytes per G chunk (9 tiles x 64 lanes x 16B)

typedef short bf16x8 __attribute__((ext_vector_type(8)));
typedef float f32x4  __attribute__((ext_vector_type(4)));

__device__ __forceinline__ unsigned short f2bf(float f) {
    uint32_t x = __float_as_uint(f);
    return (unsigned short)((x + 0x7FFFu + ((x >> 16) & 1u)) >> 16);  // RNE
}

// ---- Pass 0: bit-pack adjacency (a != 0) -> bits[b][n][96 words]; sequential HBM stream
__global__ void k_bits(const float* __restrict__ a, uint32_t* __restrict__ bits) {
    int b = blockIdx.x / N_;
    int n = blockIdx.x % N_;
    const float* row = a + (size_t)(b * N_ + n) * N_;
    uint32_t* brow = bits + (size_t)(b * N_ + n) * BITSW_;
    int wv = threadIdx.x >> 6, lane = threadIdx.x & 63;   // 256 thr = 4 waves
    for (int it = 0; it < 12; ++it) {
        int ig = wv * 12 + it;                            // 64-wide slab index, 0..46 valid
        if (ig < 47) {
            int m = ig * 64 + lane;
            float v = (m < N_) ? row[m] : 0.f;
            unsigned long long bal = __ballot(v != 0.f);
            if (lane == 0)  brow[ig * 2]     = (uint32_t)bal;
            if (lane == 32) brow[ig * 2 + 1] = (uint32_t)(bal >> 32);
        }
    }
    if (threadIdx.x == 0) { brow[94] = 0u; brow[95] = 0u; }  // pad words must be 0
}

// ---- Pass 1: feat[b][h][n][d] = h . kernel ; e2[b][h][n] = feat . att_k2 ; node_mask
__global__ void k_feat(const float* __restrict__ hin, const float* __restrict__ kern,
                       const float* __restrict__ ak2,
                       float* __restrict__ feat, float* __restrict__ e2,
                       float* __restrict__ nmask) {
    int b = blockIdx.x / N_;
    int n = blockIdx.x % N_;
    __shared__ float hrow[F_];
    int tid = threadIdx.x;                       // 128 threads: (h = tid>>5, d = tid&31)
    if (tid < F_) hrow[tid] = hin[(size_t)(b * N_ + n) * F_ + tid];
    __syncthreads();
    int hh = tid >> 5, d = tid & 31;
    float acc = 0.f;
    #pragma unroll
    for (int f = 0; f < F_; ++f)
        acc = fmaf(hrow[f], kern[(hh * F_ + f) * D_ + d], acc);
    feat[((size_t)(b * H_ + hh) * N_ + n) * D_ + d] = acc;
    float v = acc * ak2[hh * D_ + d];
    #pragma unroll
    for (int o = 16; o >= 1; o >>= 1) v += __shfl_xor(v, o, 32);
    if (d == 0) e2[(size_t)(b * H_ + hh) * N_ + n] = v;
    unsigned long long bal = __ballot(tid < F_ && hrow[tid & (F_ - 1)] != 0.0f);
    if (tid == 0) nmask[b * N_ + n] = (bal != 0ull) ? 1.0f : 0.0f;
}

// ---- Pass 2: G in MFMA-B-fragment order: G[((b*96+ch)*9+t)*64 + lane] = ushort8
//      lane: rg=lane>>4, col=lane&15 ; element j -> Gmat[m = ch*32+rg*8+j][k = t*16+col]
//      Gmat[m][k<128] = w[h][m]*feat[h][m][d] (h=k>>5,d=k&31); k in 128..131 -> w[k-128][m]; else 0
//      w[h][m] = exp(e2[h][m])  (max-subtraction cancels in the ratio; |e2|~O(1) so no overflow)
__global__ void k_G(const float* __restrict__ feat, const float* __restrict__ e2,
                    bf16x8* __restrict__ G) {
    int idx = blockIdx.x * blockDim.x + threadIdx.x;
    const int total = B_ * NCHP_ * KT_ * 64;
    if (idx >= total) return;
    int lane = idx & 63;
    int t  = (idx >> 6) % KT_;
    int ch = ((idx >> 6) / KT_) % NCHP_;
    int b  = idx / (64 * KT_ * NCHP_);
    int rg = lane >> 4, col = lane & 15;
    int k  = t * 16 + col;
    int m0 = ch * 32 + rg * 8;
    float vals[8];
    if (k < K_ + H_) {
        int hh, d; bool wonly;
        if (k < K_) { hh = k >> 5; d = k & 31; wonly = false; }
        else        { hh = k - K_; d = 0;      wonly = true;  }
        const float* e2p = e2 + (size_t)(b * H_ + hh) * N_;
        const float* fp  = feat + (size_t)(b * H_ + hh) * N_ * D_ + d;
        #pragma unroll
        for (int j = 0; j < 8; ++j) {
            int m = m0 + j;
            float v = 0.f;
            if (m < N_) {
                float w = __expf(e2p[m]);
                v = wonly ? w : w * fp[(size_t)m * D_];
            }
            vals[j] = v;
        }
    } else {
        #pragma unroll
        for (int j = 0; j < 8; ++j) vals[j] = 0.f;
    }
    union { bf16x8 v; unsigned short u[8]; } o;
    #pragma unroll
    for (int j = 0; j < 8; ++j) o.u[j] = f2bf(vals[j]);
    G[idx] = o.v;
}

// ---- Pass 3 helpers (all indices compile-time after unroll; rule #20)
template<int NT>
__device__ __forceinline__ void loadG(const char* p, bf16x8 (&g)[NT]) {
    #pragma unroll
    for (int t = 0; t < NT; ++t) g[t] = *(const bf16x8*)(p + t * 1024);
}

template<int NT>
__device__ __forceinline__ void computeG(uint32_t word, int rg,
                                         const bf16x8 (&g)[NT], f32x4 (&acc)[NT]) {
    uint32_t mb = (word >> (rg * 8)) & 0xFFu;
    union { uint32_t u[4]; bf16x8 v; } af;        // bf16 1.0 = 0x3F80, exact 0/1
    af.u[0] = ((mb & 1u)   ? 0x3F80u : 0u) | ((mb & 2u)   ? 0x3F800000u : 0u);
    af.u[1] = ((mb & 4u)   ? 0x3F80u : 0u) | ((mb & 8u)   ? 0x3F800000u : 0u);
    af.u[2] = ((mb & 16u)  ? 0x3F80u : 0u) | ((mb & 32u)  ? 0x3F800000u : 0u);
    af.u[3] = ((mb & 64u)  ? 0x3F80u : 0u) | ((mb & 128u) ? 0x3F800000u : 0u);
    #pragma unroll
    for (int t = 0; t < NT; ++t)
        acc[t] = __builtin_amdgcn_mfma_f32_16x16x32_bf16(af.v, g[t], acc[t], 0, 0, 0);
}

// one wave's full 24-chunk reduction over its NT tiles, register double-buffered
template<int T0, int NT>
__device__ __forceinline__ void waverun(const char* GsT, const uint32_t (&bw)[24],
                                        int rg, float* pout, int l) {
    f32x4 acc[NT];
    #pragma unroll
    for (int t = 0; t < NT; ++t) acc[t] = (f32x4){0.f, 0.f, 0.f, 0.f};
    bf16x8 gA[NT], gB[NT];
    loadG<NT>(GsT, gA);
    #pragma unroll
    for (int i = 0; i < 24; ++i) {
        if ((i & 1) == 0) {
            if (i + 1 < 24) loadG<NT>(GsT + (size_t)(i + 1) * CHB_, gB);
            computeG<NT>(bw[i], rg, gA, acc);
        } else {
            if (i + 1 < 24) loadG<NT>(GsT + (size_t)(i + 1) * CHB_, gA);
            computeG<NT>(bw[i], rg, gB, acc);
        }
    }
    #pragma unroll
    for (int t = 0; t < NT; ++t)
        #pragma unroll
        for (int r = 0; r < 4; ++r)
            pout[(T0 + t) * 256 + r * 64 + l] = acc[t][r];
}

// ---- Pass 3: split-K GEMM, register-only, NO LDS / NO barriers. Grid = B x NROWT x 4.
//      Block = 2 independent waves over the same 16 rows: wave0 tiles 0-4, wave1 tiles 5-8.
//      3008 waves total -> ALL resident (TLP hides load latency). Bits preloaded (6x uint4).
__global__ void __launch_bounds__(128, 4) k_main(
        const uint32_t* __restrict__ bits, const bf16x8* __restrict__ G,
        float* __restrict__ partial) {
    int bid = blockIdx.x;
    int s  = bid & 3;
    int rt = (bid >> 2) % NROWT_;
    int b  = bid / (S4_ * NROWT_);
    int w = threadIdx.x >> 6;                     // wave 0..1
    int l = threadIdx.x & 63;
    int rg = l >> 4, col = l & 15;
    int row = min(rt * 16 + col, N_ - 1);         // A-frag row (clamped; extras masked in k_red)
    const uint4* bq = (const uint4*)(bits + (size_t)(b * N_ + row) * BITSW_ + s * 24);
    uint4 b0 = bq[0], b1 = bq[1], b2 = bq[2], b3 = bq[3], b4 = bq[4], b5 = bq[5];
    uint32_t bw[24] = { b0.x, b0.y, b0.z, b0.w,  b1.x, b1.y, b1.z, b1.w,
                        b2.x, b2.y, b2.z, b2.w,  b3.x, b3.y, b3.z, b3.w,
                        b4.x, b4.y, b4.z, b4.w,  b5.x, b5.y, b5.z, b5.w };
    const char* Gs = (const char*)G + (size_t)(b * NCHP_ + s * 24) * CHB_ + (size_t)l * 16;
    float* pout = partial + (size_t)bid * PT_;
    if (w == 0) waverun<0, 5>(Gs,            bw, rg, pout, l);
    else        waverun<5, 4>(Gs + 5 * 1024, bw, rg, pout, l);
}

// ---- Pass 4: sum 4 partials per 16-row tile + fused epilogue (divide/bias/relu/mask)
__global__ void __launch_bounds__(256) k_red(
        const float* __restrict__ partial, const float* __restrict__ bias,
        const float* __restrict__ nmask, float* __restrict__ out) {
    int rt = blockIdx.x % NROWT_;
    int b  = blockIdx.x / NROWT_;
    int nbase = rt * 16;
    int tid = threadIdx.x;
    __shared__ float sm[PT_];
    const float* pbase = partial + (size_t)((b * NROWT_ + rt) * S4_) * PT_;
    #pragma unroll
    for (int k = 0; k < 9; ++k) {
        int flat = tid + k * 256;
        float s = 0.f;
        #pragma unroll
        for (int sp = 0; sp < S4_; ++sp) s += pbase[(size_t)sp * PT_ + flat];
        sm[flat] = s;
    }
    __syncthreads();
    #pragma unroll
    for (int k = 0; k < 9; ++k) {
        int flat = tid + k * 256;
        if (flat < 2048) {                        // tiles 0..7 are outputs
            int t4r = flat >> 6;                  // t*4+r
            int t = t4r >> 2, r = t4r & 3;
            int lane = flat & 63;
            int rg = lane >> 4, col = lane & 15;
            int rowi = rg * 4 + r;
            int n = nbase + rowi;
            if (n < N_) {
                int hh = t >> 1;
                int r2 = rowi & 3, rg2 = rowi >> 2;
                float den = sm[(32 + r2) * 64 + (rg2 << 4) + hh];
                float v = (den > 0.f) ? sm[flat] / den : 0.f;
                v += bias[t * 16 + col];
                v = fmaxf(v, 0.f);
                v *= nmask[b * N_ + n];
                out[(size_t)(b * N_ + n) * K_ + t * 16 + col] = v;
            }
        }
    }
}

extern "C" void kernel_launch(void* const* d_in, const int* in_sizes, int n_in,
                              void* d_out, int out_size, void* d_ws, size_t ws_size,
                              hipStream_t stream) {
    const float* h    = (const float*)d_in[0];
    const float* a    = (const float*)d_in[1];
    const float* kern = (const float*)d_in[2];
    // d_in[3] = att_k1: cancels in row-softmax, unused
    const float* ak2  = (const float*)d_in[4];
    const float* bias = (const float*)d_in[5];
    float* out = (float*)d_out;

    char* ws = (char*)d_ws;
    size_t o_feat  = 0;                                   // 3,072,000 B
    size_t o_e2    = o_feat  + 3072000;                   //    96,000 B
    size_t o_nmask = o_e2    + 96000;                     //    24,064 B (pad)
    size_t o_bits  = o_nmask + 24064;                     // 6000*96*4 = 2,304,000 B
    size_t o_G     = o_bits  + 2304000;                   // 2*96*9216 = 1,769,472 B
    size_t o_part  = o_G     + 1769472;                   // 1504*9216 = 13,860,864 B
    float*    feat  = (float*)(ws + o_feat);
    float*    e2    = (float*)(ws + o_e2);
    float*    nmask = (float*)(ws + o_nmask);
    uint32_t* bits  = (uint32_t*)(ws + o_bits);
    bf16x8*   G     = (bf16x8*)(ws + o_G);
    float*    part  = (float*)(ws + o_part);

    k_bits<<<dim3(B_ * N_), dim3(256), 0, stream>>>(a, bits);
    k_feat<<<dim3(B_ * N_), dim3(128), 0, stream>>>(h, kern, ak2, feat, e2, nmask);
    int gtot = B_ * NCHP_ * KT_ * 64;
    k_G   <<<dim3((gtot + 255) / 256), dim3(256), 0, stream>>>(feat, e2, G);
    k_main<<<dim3(B_ * NROWT_ * S4_), dim3(128), 0, stream>>>(bits, G, part);
    k_red <<<dim3(B_ * NROWT_), dim3(256), 0, stream>>>(part, bias, nmask, out);
}

// Round 10
// 52.020 us; speedup vs baseline: 1.3090x; 1.3090x over previous
//
#include <hip/hip_runtime.h>
#include <hip/hip_bf16.h>
#include <stdint.h>

#define B_ 2
#define N_ 3000
#define F_ 64
#define H_ 4
#define D_ 32
#define K_ 128          // H_*D_ output feature cols
#define KT_ 9           // 9 k-tiles of 16 -> 144 cols (128 feat + 4 denom + 12 pad)
#define NCH_ 94         // ceil(3000/32) m-chunks (3008 padded)
#define NROWT_ 188      // ceil(3000/16) row tiles per batch
#define NW_ 8           // waves per k_main block

typedef short bf16x8 __attribute__((ext_vector_type(8)));
typedef float f32x4  __attribute__((ext_vector_type(4)));

__device__ __forceinline__ unsigned short f2bf(float f) {
    uint32_t x = __float_as_uint(f);
    return (unsigned short)((x + 0x7FFFu + ((x >> 16) & 1u)) >> 16);  // RNE
}

// ---- Pass 1: feat[b][h][n][d] = h . kernel ; e2[b][h][n] = feat . att_k2 ; node_mask
__global__ void k_feat(const float* __restrict__ hin, const float* __restrict__ kern,
                       const float* __restrict__ ak2,
                       float* __restrict__ feat, float* __restrict__ e2,
                       float* __restrict__ nmask) {
    int b = blockIdx.x / N_;
    int n = blockIdx.x % N_;
    __shared__ float hrow[F_];
    int tid = threadIdx.x;                       // 128 threads: (h = tid>>5, d = tid&31)
    if (tid < F_) hrow[tid] = hin[(size_t)(b * N_ + n) * F_ + tid];
    __syncthreads();
    int hh = tid >> 5, d = tid & 31;
    float acc = 0.f;
    #pragma unroll
    for (int f = 0; f < F_; ++f)
        acc = fmaf(hrow[f], kern[(hh * F_ + f) * D_ + d], acc);
    feat[((size_t)(b * H_ + hh) * N_ + n) * D_ + d] = acc;
    float v = acc * ak2[hh * D_ + d];
    #pragma unroll
    for (int o = 16; o >= 1; o >>= 1) v += __shfl_xor(v, o, 32);
    if (d == 0) e2[(size_t)(b * H_ + hh) * N_ + n] = v;
    unsigned long long bal = __ballot(tid < F_ && hrow[tid & (F_ - 1)] != 0.0f);
    if (tid == 0) nmask[b * N_ + n] = (bal != 0ull) ? 1.0f : 0.0f;
}

// ---- Pass 2: G in MFMA-B-fragment order: G[((b*94+ch)*9+t)*64 + lane] = ushort8
//      lane: rg=lane>>4, col=lane&15 ; element j -> Gmat[m = ch*32+rg*8+j][k = t*16+col]
//      Gmat[m][k<128] = w[h][m]*feat[h][m][d] (h=k>>5,d=k&31); k in 128..131 -> w[k-128][m]; else 0
//      w[h][m] = exp(e2[h][m])  (max cancels in the num/den ratio; |e2|~O(1), no overflow)
__global__ void k_G(const float* __restrict__ feat, const float* __restrict__ e2,
                    bf16x8* __restrict__ G) {
    int idx = blockIdx.x * blockDim.x + threadIdx.x;
    const int total = B_ * NCH_ * KT_ * 64;
    if (idx >= total) return;
    int lane = idx & 63;
    int t  = (idx >> 6) % KT_;
    int ch = ((idx >> 6) / KT_) % NCH_;
    int b  = idx / (64 * KT_ * NCH_);
    int rg = lane >> 4, col = lane & 15;
    int k  = t * 16 + col;
    int m0 = ch * 32 + rg * 8;
    float vals[8];
    if (k < K_ + H_) {
        int hh, d; bool wonly;
        if (k < K_) { hh = k >> 5; d = k & 31; wonly = false; }
        else        { hh = k - K_; d = 0;      wonly = true;  }
        const float* e2p = e2 + (size_t)(b * H_ + hh) * N_;
        const float* fp  = feat + (size_t)(b * H_ + hh) * N_ * D_ + d;
        #pragma unroll
        for (int j = 0; j < 8; ++j) {
            int m = m0 + j;
            float v = 0.f;
            if (m < N_) {
                float w = __expf(e2p[m]);
                v = wonly ? w : w * fp[(size_t)m * D_];
            }
            vals[j] = v;
        }
    } else {
        #pragma unroll
        for (int j = 0; j < 8; ++j) vals[j] = 0.f;
    }
    union { bf16x8 v; unsigned short u[8]; } o;
    #pragma unroll
    for (int j = 0; j < 8; ++j) o.u[j] = f2bf(vals[j]);
    G[idx] = o.v;
}

// ---- Pass 3 helpers: register double-buffered load set + MFMA compute (R5-proven math)
__device__ __forceinline__ void loadsetA(const float* __restrict__ arow, int ch, int rg,
                                         f32x4& f0, f32x4& f1) {
    if (ch == NCH_ - 1 && rg == 3) {              // m=3000..3007: out of range
        f0 = (f32x4){0.f, 0.f, 0.f, 0.f};
        f1 = (f32x4){0.f, 0.f, 0.f, 0.f};
    } else {
        const f32x4* p = (const f32x4*)(arow + ch * 32 + rg * 8);
        f0 = p[0]; f1 = p[1];
    }
}

__device__ __forceinline__ void loadsetG(const bf16x8* __restrict__ Gb, int ch,
                                         bf16x8 (&g)[KT_]) {
    const bf16x8* p = Gb + (size_t)ch * KT_ * 64;
    #pragma unroll
    for (int t = 0; t < KT_; ++t) g[t] = p[t * 64];
}

__device__ __forceinline__ void computeset(const f32x4& f0, const f32x4& f1,
                                           const bf16x8 (&g)[KT_], f32x4 (&acc)[KT_]) {
    union { uint32_t u[4]; bf16x8 v; } af;        // bf16 1.0 = 0x3F80, exact 0/1
    af.u[0] = ((f0.x != 0.f) ? 0x3F80u : 0u) | ((f0.y != 0.f) ? 0x3F800000u : 0u);
    af.u[1] = ((f0.z != 0.f) ? 0x3F80u : 0u) | ((f0.w != 0.f) ? 0x3F800000u : 0u);
    af.u[2] = ((f1.x != 0.f) ? 0x3F80u : 0u) | ((f1.y != 0.f) ? 0x3F800000u : 0u);
    af.u[3] = ((f1.z != 0.f) ? 0x3F80u : 0u) | ((f1.w != 0.f) ? 0x3F800000u : 0u);
    #pragma unroll
    for (int t = 0; t < KT_; ++t)
        acc[t] = __builtin_amdgcn_mfma_f32_16x16x32_bf16(af.v, g[t], acc[t], 0, 0, 0);
}

// ---- Pass 3: main GEMM, adjacency read fused. 8 waves/block; wave w reduces
//      ~12 of 94 m-chunks for the same 16 rows x 144 cols; LDS cross-wave reduction
//      + fused softmax-divide/bias/relu/mask epilogue. launch_bounds(512,2): VGPR cap
//      256 so the register double-buffer survives (R5/R6 failed at cap 128).
__global__ void __launch_bounds__(512, 2) k_main(
        const float* __restrict__ a, const bf16x8* __restrict__ G,
        const float* __restrict__ bias, const float* __restrict__ nmask,
        float* __restrict__ out) {
    int blk = blockIdx.x;
    int b  = blk / NROWT_;
    int rt = blk % NROWT_;
    int nbase = rt * 16;
    int w = threadIdx.x >> 6;                     // wave 0..7
    int l = threadIdx.x & 63;
    int rg = l >> 4, col = l & 15;
    int arow_i = nbase + col;                     // A-frag row = lane&15
    int aclamp = min(arow_i, N_ - 1);
    const float* arow = a + (size_t)(b * N_ + aclamp) * N_;
    const bf16x8* Gb = G + (size_t)b * NCH_ * KT_ * 64 + l;

    // wave w's chunk range: lens 11,12,12,12,11,12,12,12 (sum 94)
    int c0 = (w * NCH_) / NW_;
    int c1 = ((w + 1) * NCH_) / NW_;

    f32x4 acc[KT_];
    #pragma unroll
    for (int t = 0; t < KT_; ++t) acc[t] = (f32x4){0.f, 0.f, 0.f, 0.f};

    // software pipeline: prefetch set B while computing set A (all 11 loads in flight)
    f32x4 aA0, aA1, aB0, aB1;
    bf16x8 gA[KT_], gB[KT_];
    loadsetA(arow, c0, rg, aA0, aA1);
    loadsetG(Gb, c0, gA);
    int ch = c0;
    for (;;) {
        if (ch + 1 < c1) { loadsetA(arow, ch + 1, rg, aB0, aB1); loadsetG(Gb, ch + 1, gB); }
        computeset(aA0, aA1, gA, acc);
        if (++ch >= c1) break;
        if (ch + 1 < c1) { loadsetA(arow, ch + 1, rg, aA0, aA1); loadsetG(Gb, ch + 1, gA); }
        computeset(aB0, aB1, gB, acc);
        if (++ch >= c1) break;
    }

    // cross-wave reduction in LDS (8-way)
    __shared__ float red[NW_][KT_ * 4][64];       // 73,728 B
    __shared__ float dl[16][4];
    #pragma unroll
    for (int t = 0; t < KT_; ++t)
        #pragma unroll
        for (int r = 0; r < 4; ++r)
            red[w][t * 4 + r][l] = acc[t][r];
    __syncthreads();

    // sum 8 partials into red[0]
    #pragma unroll
    for (int k = 0; k < 5; ++k) {
        int flat = threadIdx.x + k * 512;         // 0..2303
        if (flat < KT_ * 4 * 64) {
            int x = flat >> 6, y = flat & 63;
            float s = red[0][x][y];
            #pragma unroll
            for (int ww = 1; ww < NW_; ++ww) s += red[ww][x][y];
            red[0][x][y] = s;
        }
    }
    __syncthreads();

    // denominators from tile 8, cols 0..3: value (r, lane=(rg<<4)|hh) -> row rg*4+r, head hh
    if (threadIdx.x < 64) {
        int rowi = threadIdx.x >> 2;              // 0..15
        int hh   = threadIdx.x & 3;               // 0..3
        int rg2 = rowi >> 2, r2 = rowi & 3;
        dl[rowi][hh] = red[0][32 + r2][(rg2 << 4) | hh];
    }
    __syncthreads();

    // outputs: tiles 0..7 (32 t4r combos x 64 lanes), 4 per thread
    #pragma unroll
    for (int i = 0; i < 4; ++i) {
        int t4r = i * NW_ + w;                    // 0..31
        int t = t4r >> 2, r = t4r & 3;
        int rowi = rg * 4 + r;                    // D row = (lane>>4)*4 + reg
        int n = nbase + rowi;
        if (n < N_) {
            float s = red[0][t4r][l];
            int hh = t >> 1;
            float den = dl[rowi][hh];
            float v = (den > 0.f) ? s / den : 0.f;
            v += bias[t * 16 + col];
            v = fmaxf(v, 0.f);
            v *= nmask[b * N_ + n];
            out[(size_t)(b * N_ + n) * K_ + t * 16 + col] = v;
        }
    }
}

extern "C" void kernel_launch(void* const* d_in, const int* in_sizes, int n_in,
                              void* d_out, int out_size, void* d_ws, size_t ws_size,
                              hipStream_t stream) {
    const float* h    = (const float*)d_in[0];
    const float* a    = (const float*)d_in[1];
    const float* kern = (const float*)d_in[2];
    // d_in[3] = att_k1: cancels in row-softmax, unused
    const float* ak2  = (const float*)d_in[4];
    const float* bias = (const float*)d_in[5];
    float* out = (float*)d_out;

    char* ws = (char*)d_ws;
    size_t o_feat  = 0;                                   // 3,072,000 B
    size_t o_e2    = o_feat  + 3072000;                   //    96,000 B
    size_t o_nmask = o_e2    + 96000;                     //    24,064 B (pad)
    size_t o_G     = o_nmask + 24064;                     // 108288 * 16 B = 1,732,608 B
    float*  feat  = (float*)(ws + o_feat);
    float*  e2    = (float*)(ws + o_e2);
    float*  nmask = (float*)(ws + o_nmask);
    bf16x8* G     = (bf16x8*)(ws + o_G);

    k_feat<<<dim3(B_ * N_), dim3(128), 0, stream>>>(h, kern, ak2, feat, e2, nmask);
    int gtot = B_ * NCH_ * KT_ * 64;
    k_G   <<<dim3((gtot + 255) / 256), dim3(256), 0, stream>>>(feat, e2, G);
    k_main<<<dim3(B_ * NROWT_), dim3(512), 0, stream>>>(a, G, bias, nmask, out);
}